// Round 4
// baseline (1763.711 us; speedup 1.0000x reference)
//
#include <hip/hip_runtime.h>
#include <stdint.h>

// ---------------- problem constants ----------------
#define CH 512
#define W1 96
#define P1 (W1*W1)        // 9216 descriptor pixels per map
#define W2 192
#define P2 (W2*W2)        // 36864 activation pixels per map
#define BM 256
#define BN 256
#define NTT 36            // 9216/256 tiles per dimension
#define BK 32             // K-chunk
#define NKS (CH/BK)       // 16 K-steps
#define EPSF 1e-8f
#define RDENSE 0.95f
#define RREFINE 0.9f

typedef __attribute__((ext_vector_type(8))) short bf16x8_t;
typedef __attribute__((ext_vector_type(4))) float f32x4_t;

// ---- packed (value,index): total order, ties -> lower index wins ----
__device__ __forceinline__ unsigned enc_f32(float f){
  unsigned u = __float_as_uint(f);
  return (u & 0x80000000u) ? ~u : (u | 0x80000000u);
}
__device__ __forceinline__ float dec_f32(unsigned e){
  unsigned u = (e & 0x80000000u) ? (e & 0x7FFFFFFFu) : ~e;
  return __uint_as_float(u);
}
__device__ __forceinline__ unsigned long long packVI(float v, int idx){
  return (((unsigned long long)enc_f32(v)) << 32) | (unsigned)(~(unsigned)idx);
}
__device__ __forceinline__ float packedVal(unsigned long long p){ return dec_f32((unsigned)(p >> 32)); }
__device__ __forceinline__ int packedIdx(unsigned long long p){ return (int)(~(unsigned)(p & 0xFFFFFFFFull)); }
__device__ __forceinline__ void merge2(unsigned long long &b, unsigned long long &s, unsigned long long c){
  if (c > b){ s = b; b = c; } else if (c > s){ s = c; }
}

// bf16 round-to-nearest-even
__device__ __forceinline__ unsigned short f2bf(float f){
  unsigned u = __float_as_uint(f);
  unsigned r = (u + 0x7FFFu + ((u >> 16) & 1u)) >> 16;
  return (unsigned short)r;
}

__device__ __forceinline__ void gload16(const void* g, void* l){
  __builtin_amdgcn_global_load_lds(
      (const __attribute__((address_space(1))) unsigned int*)g,
      (__attribute__((address_space(3))) unsigned int*)l, 16, 0, 0);
}

// ---------------- 1. descriptor inverse norms ----------------
__global__ void desc_norm(const float* __restrict__ mA, const float* __restrict__ mB,
                          float* __restrict__ inv1, float* __restrict__ inv2){
  int p = blockIdx.x * blockDim.x + threadIdx.x;
  const float* m = (p < P1) ? mA : mB;
  float* o = (p < P1) ? inv1 : inv2;
  int pix = (p < P1) ? p : p - P1;
  float s = 0.f;
  for (int c = 0; c < CH; ++c){ float v = m[c*P1 + pix]; s += v*v; }
  o[pix] = 1.0f / sqrtf(s);
}

// ---------------- 2. activation inverse norms ----------------
__global__ void act_norm(const float* __restrict__ aA, const float* __restrict__ aB,
                         float* __restrict__ invA, float* __restrict__ invB){
  int p = blockIdx.x * blockDim.x + threadIdx.x;
  const float* m = (p < P2) ? aA : aB;
  float* o = (p < P2) ? invA : invB;
  int pix = (p < P2) ? p : p - P2;
  float s = 0.f;
  for (int c = 0; c < CH; ++c){ float v = m[(size_t)c*P2 + pix]; s += v*v; }
  o[pix] = 1.0f / sqrtf(s);
}

// ---------------- 2b. normalize + split fp32 -> bf16 hi/lo, K-MAJOR layout ----------------
// out layout: panel[kb][pix][32] bf16, kb = c/32. Within each row (32 ch = 4 chunks of
// 16 B), chunks stored permuted: stored_chunk = logical_chunk ^ ((pix>>1)&3), so that
// LINEAR global_load_lds staging lands the XOR-swizzle in LDS (rule #21: swizzle both
// sides via pre-permuted source; ds_read applies the same XOR).
__global__ __launch_bounds__(256)
void prep_split(const float* __restrict__ src, const float* __restrict__ inv,
                unsigned short* __restrict__ hi, unsigned short* __restrict__ lo){
  __shared__ float tile[64][65];
  const int pixBase = blockIdx.x * 64;
  const int chBase  = blockIdx.y * 64;
  const int t = threadIdx.x;
  #pragma unroll
  for (int rep = 0; rep < 16; ++rep){
    int idx = rep*256 + t;
    int c = idx >> 6, p = idx & 63;
    tile[c][p] = src[(chBase + c)*P1 + pixBase + p];
  }
  __syncthreads();
  const int p = t >> 2, cg = (t & 3) * 16;
  const int pix = pixBase + p;
  const float iv = inv[pix];
  unsigned short hbuf[16], lbuf[16];
  #pragma unroll
  for (int j = 0; j < 16; ++j){
    float v = tile[cg + j][p] * iv;
    unsigned short h = f2bf(v);
    float hv = __uint_as_float((unsigned)h << 16);
    lbuf[j] = f2bf(v - hv);
    hbuf[j] = h;
  }
  const int c0 = chBase + cg;
  const int kb = c0 >> 5;             // K-block index (16 channels stay in one kb)
  const int ck0 = (c0 & 31) >> 3;     // logical chunk 0 or 2
  const int sz = (pix >> 1) & 3;
  size_t base = (size_t)kb*(P1*32) + (size_t)pix*32;
  *(uint4*)(hi + base + ((ck0    ^sz)<<3)) = ((const uint4*)hbuf)[0];
  *(uint4*)(hi + base + (((ck0+1)^sz)<<3)) = ((const uint4*)hbuf)[1];
  *(uint4*)(lo + base + ((ck0    ^sz)<<3)) = ((const uint4*)lbuf)[0];
  *(uint4*)(lo + base + (((ck0+1)^sz)<<3)) = ((const uint4*)lbuf)[1];
}

// ---------------- 3. MFMA sim-GEMM, 256x256 tile, dbuf 2-phase, contiguous staging ----
// 8 waves (2x4), wave tile 128x64 (8x4 frags of 16x16x32), 3-pass split bf16.
// Panels are K-major: each K-step's 16KB panel slice is CONTIGUOUS in global; each
// global_load_lds reads 1KB linearly. LDS: 2 x 64KB dbuf {Ah,Al,Bh,Bl}[256 rows][32k].
__global__ __launch_bounds__(512, 2)
void sim_mfma(const unsigned short* __restrict__ Ah, const unsigned short* __restrict__ Al,
              const unsigned short* __restrict__ Bh, const unsigned short* __restrict__ Bl,
              unsigned long long* __restrict__ rowCand,
              unsigned long long* __restrict__ colCand){
  __shared__ __align__(16) char lds[131072];    // 2 x 64KB

  const int nwg = NTT*NTT;                      // 1296, %8==0 -> bijective
  int bid = blockIdx.x;
  int swz = (bid & 7) * (nwg >> 3) + (bid >> 3);
  const int rt = swz / NTT, ct = swz % NTT;
  const int rBase = rt * BM, cBase = ct * BN;

  const int t = threadIdx.x;
  const int w = t >> 6, lane = t & 63;
  const int wr = w >> 2, wc = w & 3;            // wave grid 2x4
  const int l15 = lane & 15, lj = lane >> 4;

  // staging: wave w = (panel = w>>1, sub = w&1); stages rows [sub*128, sub*128+128)
  // of its panel's tile slice = 8KB contiguous = 8 x 1KB linear loads.
  const int panel = w >> 1, sub = w & 1;
  const unsigned short* pptr = (panel==0)?Ah:(panel==1)?Al:(panel==2)?Bh:Bl;
  const int Base = (panel < 2) ? rBase : cBase;
  const char* gpan = (const char*)pptr + (size_t)Base*64 + sub*8192;
  char* ldsPan0 = lds + panel*16384 + sub*8192;

  // fragment LDS byte-offsets (row*64 + swizzled_chunk*16)
  int aOff[8], bOff[4];
  #pragma unroll
  for (int mi = 0; mi < 8; ++mi){
    int rA = wr*128 + mi*16 + l15;
    aOff[mi] = rA*64 + ((lj ^ ((rA >> 1) & 3)) << 4);
  }
  #pragma unroll
  for (int ni = 0; ni < 4; ++ni){
    int rB = wc*64 + ni*16 + l15;
    bOff[ni] = rB*64 + ((lj ^ ((rB >> 1) & 3)) << 4);
  }

  f32x4_t acc[8][4];
  #pragma unroll
  for (int i = 0; i < 8; ++i)
    #pragma unroll
    for (int j = 0; j < 4; ++j)
      #pragma unroll
      for (int r = 0; r < 4; ++r) acc[i][j][r] = 0.f;

  // ---- prologue: stage K-step 0 into buf0 ----
  #pragma unroll
  for (int i = 0; i < 8; ++i)
    gload16(gpan + i*1024 + lane*16, ldsPan0 + i*1024);
  __syncthreads();

  // ---- main loop: 2-phase double-buffered ----
  for (int ks = 0; ks < NKS; ++ks){
    const int cur = ks & 1;
    if (ks + 1 < NKS){
      const char* gb = gpan + (size_t)(ks+1)*(P1*64);
      char* lb = ldsPan0 + (cur^1)*65536;
      #pragma unroll
      for (int i = 0; i < 8; ++i)
        gload16(gb + i*1024 + lane*16, lb + i*1024);
    }
    const char* bp = lds + cur*65536;
    bf16x8_t ahf[8], alf[8];
    #pragma unroll
    for (int mi = 0; mi < 8; ++mi){
      ahf[mi] = *(const bf16x8_t*)(bp + aOff[mi]);
      alf[mi] = *(const bf16x8_t*)(bp + 16384 + aOff[mi]);
    }
    __builtin_amdgcn_s_setprio(1);
    #pragma unroll
    for (int ni = 0; ni < 4; ++ni){
      bf16x8_t bhf = *(const bf16x8_t*)(bp + 32768 + bOff[ni]);
      bf16x8_t blf = *(const bf16x8_t*)(bp + 49152 + bOff[ni]);
      #pragma unroll
      for (int mi = 0; mi < 8; ++mi){
        acc[mi][ni] = __builtin_amdgcn_mfma_f32_16x16x32_bf16(ahf[mi], bhf, acc[mi][ni], 0, 0, 0);
        acc[mi][ni] = __builtin_amdgcn_mfma_f32_16x16x32_bf16(ahf[mi], blf, acc[mi][ni], 0, 0, 0);
        acc[mi][ni] = __builtin_amdgcn_mfma_f32_16x16x32_bf16(alf[mi], bhf, acc[mi][ni], 0, 0, 0);
      }
    }
    __builtin_amdgcn_s_setprio(0);
    __syncthreads();   // drains this step's stage loads after the compute window
  }

  // ---- fused top-2 epilogue. C/D layout: col=lane&15, row=(lane>>4)*4+reg ----
  unsigned long long (*rowScr)[4][2] = (unsigned long long (*)[4][2])(lds);          // 16KB
  unsigned long long (*colScr)[2][2] = (unsigned long long (*)[2][2])(lds + 16384);  // 8KB

  #pragma unroll
  for (int mi = 0; mi < 8; ++mi){
    #pragma unroll
    for (int reg = 0; reg < 4; ++reg){
      unsigned long long b = 0ull, s = 0ull;
      #pragma unroll
      for (int ni = 0; ni < 4; ++ni){
        int col = cBase + wc*64 + ni*16 + l15;
        merge2(b, s, packVI(acc[mi][ni][reg], col));
      }
      #pragma unroll
      for (int m = 1; m < 16; m <<= 1){
        unsigned long long ob = __shfl_xor(b, m, 64);
        unsigned long long os = __shfl_xor(s, m, 64);
        merge2(b, s, ob); merge2(b, s, os);
      }
      if (l15 == 0){
        int rowLoc = wr*128 + mi*16 + lj*4 + reg;
        rowScr[rowLoc][wc][0] = b; rowScr[rowLoc][wc][1] = s;
      }
    }
  }
  #pragma unroll
  for (int ni = 0; ni < 4; ++ni){
    unsigned long long b = 0ull, s = 0ull;
    #pragma unroll
    for (int mi = 0; mi < 8; ++mi)
      #pragma unroll
      for (int reg = 0; reg < 4; ++reg){
        int row = rBase + wr*128 + mi*16 + lj*4 + reg;
        merge2(b, s, packVI(acc[mi][ni][reg], row));
      }
    #pragma unroll
    for (int m = 16; m < 64; m <<= 1){
      unsigned long long ob = __shfl_xor(b, m, 64);
      unsigned long long os = __shfl_xor(s, m, 64);
      merge2(b, s, ob); merge2(b, s, os);
    }
    if (lj == 0){
      int colLoc = wc*64 + ni*16 + l15;
      colScr[colLoc][wr][0] = b; colScr[colLoc][wr][1] = s;
    }
  }
  __syncthreads();
  if (t < 256){
    unsigned long long b = 0ull, s = 0ull;
    #pragma unroll
    for (int j = 0; j < 4; ++j){ merge2(b, s, rowScr[t][j][0]); merge2(b, s, rowScr[t][j][1]); }
    rowCand[((long long)ct*P1 + rBase + t)*2 + 0] = b;
    rowCand[((long long)ct*P1 + rBase + t)*2 + 1] = s;
  } else {
    int c = t - 256;
    unsigned long long b = 0ull, s = 0ull;
    #pragma unroll
    for (int j = 0; j < 2; ++j){ merge2(b, s, colScr[c][j][0]); merge2(b, s, colScr[c][j][1]); }
    colCand[((long long)rt*P1 + cBase + c)*2 + 0] = b;
    colCand[((long long)rt*P1 + cBase + c)*2 + 1] = s;
  }
}

// ---------------- 4. merge per-tile candidates -> global top-2 ----------------
__global__ void merge_cand(const unsigned long long* __restrict__ cand,
                           unsigned long long* __restrict__ top,
                           unsigned long long* __restrict__ sec){
  int p = blockIdx.x * blockDim.x + threadIdx.x;
  unsigned long long b = 0ull, s = 0ull;
  for (int tile = 0; tile < NTT; ++tile){
    merge2(b, s, cand[((long long)tile*P1 + p)*2 + 0]);
    merge2(b, s, cand[((long long)tile*P1 + p)*2 + 1]);
  }
  top[p] = b; sec[p] = s;
}

// ---------------- 5. mutual-NN + ratio + border mask ----------------
__global__ void match_k(const unsigned long long* __restrict__ rowTop,
                        const unsigned long long* __restrict__ rowSec,
                        const unsigned long long* __restrict__ colTop,
                        const unsigned long long* __restrict__ colSec,
                        int4* __restrict__ pts, int* __restrict__ validArr){
  int p = blockIdx.x * blockDim.x + threadIdx.x;
  unsigned long long rT = rowTop[p], rS = rowSec[p];
  float s0 = packedVal(rT), s1 = packedVal(rS);
  int nn12 = packedIdx(rT);
  float r12 = (2.f - 2.f*s0) / (2.f - 2.f*s1 + EPSF);
  unsigned long long cT = colTop[nn12], cS = colSec[nn12];
  int nn21 = packedIdx(cT);
  float r21 = (2.f - 2.f*packedVal(cT)) / (2.f - 2.f*packedVal(cS) + EPSF);
  int xA = p % W1, yA = p / W1, xB = nn12 % W1, yB = nn12 / W1;
  bool border = (xA==0)||(xA==W1-1)||(yA==0)||(yA==W1-1)||
                (xB==0)||(xB==W1-1)||(yB==0)||(yB==W1-1);
  bool valid = (nn21 == p) && (r12 <= RDENSE) && (r21 <= RDENSE) && !border;
  pts[p] = valid ? make_int4(xA,yA,xB,yB) : make_int4(0,0,0,0);
  validArr[p] = valid ? 1 : 0;
}

// ---------------- 6a. activation transpose: [512][P2] -> [P2][512] fp32 ----------------
__global__ __launch_bounds__(256)
void act_transpose(const float* __restrict__ aA, const float* __restrict__ aB,
                   float* __restrict__ tA, float* __restrict__ tB){
  __shared__ float tile[64][65];
  const int pixBase = blockIdx.x * 64;
  const int chBase  = blockIdx.y * 64;
  const float* src = blockIdx.z ? aB : aA;
  float*       dst = blockIdx.z ? tB : tA;
  const int t = threadIdx.x;
  #pragma unroll
  for (int rep = 0; rep < 16; ++rep){
    int idx = rep*256 + t;
    int c = idx >> 6, p = idx & 63;
    tile[c][p] = src[(size_t)(chBase + c)*P2 + pixBase + p];
  }
  __syncthreads();
  const int p = t >> 2, cg = (t & 3) * 16;
  size_t base = (size_t)(pixBase + p)*CH + chBase + cg;
  #pragma unroll
  for (int q = 0; q < 4; ++q){
    float4 v = make_float4(tile[cg+q*4+0][p], tile[cg+q*4+1][p],
                           tile[cg+q*4+2][p], tile[cg+q*4+3][p]);
    *(float4*)(dst + base + q*4) = v;
  }
}

// ---------------- 6b. refine with transposed activations (coalesced) ----------------
__global__ __launch_bounds__(256)
void refine_t(const float* __restrict__ tA, const float* __restrict__ tB,
              const float* __restrict__ invA, const float* __restrict__ invB,
              const int4* __restrict__ pts, float* __restrict__ scoresOut){
  int p = (blockIdx.x * blockDim.x + threadIdx.x) >> 6;
  int lane = threadIdx.x & 63;
  int4 q = pts[p];
  const int nbx[4] = {0,0,1,1}, nby[4] = {0,1,0,1};
  int offA[4], offB[4];
  #pragma unroll
  for (int i = 0; i < 4; ++i){
    offA[i] = (2*q.y + nby[i])*W2 + 2*q.x + nbx[i];
    offB[i] = (2*q.w + nby[i])*W2 + 2*q.z + nbx[i];
  }
  float a[4][8], b[4][8];
  #pragma unroll
  for (int i = 0; i < 4; ++i){
    const float* pa = tA + (size_t)offA[i]*CH + lane*8;
    *(float4*)&a[i][0] = *(const float4*)pa;
    *(float4*)&a[i][4] = *(const float4*)(pa + 4);
    const float* pb = tB + (size_t)offB[i]*CH + lane*8;
    *(float4*)&b[i][0] = *(const float4*)pb;
    *(float4*)&b[i][4] = *(const float4*)(pb + 4);
  }
  float acc[16] = {};
  #pragma unroll
  for (int ch = 0; ch < 8; ++ch)
    #pragma unroll
    for (int i = 0; i < 4; ++i)
      #pragma unroll
      for (int j = 0; j < 4; ++j)
        acc[i*4+j] = fmaf(a[i][ch], b[j][ch], acc[i*4+j]);
  #pragma unroll
  for (int m = 1; m < 64; m <<= 1)
    #pragma unroll
    for (int u = 0; u < 16; ++u) acc[u] += __shfl_xor(acc[u], m, 64);
  if (lane == 0){
    float sA[4], sB[4];
    #pragma unroll
    for (int i = 0; i < 4; ++i){ sA[i] = invA[offA[i]]; sB[i] = invB[offB[i]]; }
    float4* o = (float4*)(scoresOut + p*16);
    #pragma unroll
    for (int i = 0; i < 4; ++i)
      o[i] = make_float4(acc[i*4+0]*sA[i]*sB[0], acc[i*4+1]*sA[i]*sB[1],
                         acc[i*4+2]*sA[i]*sB[2], acc[i*4+3]*sA[i]*sB[3]);
  }
}

// ---------------- 6c. fallback refine (original layout, gathered) ----------------
__global__ __launch_bounds__(256)
void refine(const float* __restrict__ actA, const float* __restrict__ actB,
            const float* __restrict__ invA, const float* __restrict__ invB,
            const int4* __restrict__ pts, float* __restrict__ scoresOut){
  int p = (blockIdx.x * blockDim.x + threadIdx.x) >> 6;
  int lane = threadIdx.x & 63;
  int4 q = pts[p];
  const int nbx[4] = {0,0,1,1}, nby[4] = {0,1,0,1};
  int offA[4], offB[4];
  #pragma unroll
  for (int i = 0; i < 4; ++i){
    offA[i] = (2*q.y + nby[i])*W2 + 2*q.x + nbx[i];
    offB[i] = (2*q.w + nby[i])*W2 + 2*q.z + nbx[i];
  }
  float acc[16] = {};
  #pragma unroll
  for (int k = 0; k < 8; ++k){
    int c = lane + 64*k;
    size_t base = (size_t)c * P2;
    float a0 = actA[base+offA[0]], a1 = actA[base+offA[1]],
          a2 = actA[base+offA[2]], a3 = actA[base+offA[3]];
    float b0 = actB[base+offB[0]], b1 = actB[base+offB[1]],
          b2 = actB[base+offB[2]], b3 = actB[base+offB[3]];
    acc[ 0] = fmaf(a0,b0,acc[ 0]); acc[ 1] = fmaf(a0,b1,acc[ 1]);
    acc[ 2] = fmaf(a0,b2,acc[ 2]); acc[ 3] = fmaf(a0,b3,acc[ 3]);
    acc[ 4] = fmaf(a1,b0,acc[ 4]); acc[ 5] = fmaf(a1,b1,acc[ 5]);
    acc[ 6] = fmaf(a1,b2,acc[ 6]); acc[ 7] = fmaf(a1,b3,acc[ 7]);
    acc[ 8] = fmaf(a2,b0,acc[ 8]); acc[ 9] = fmaf(a2,b1,acc[ 9]);
    acc[10] = fmaf(a2,b2,acc[10]); acc[11] = fmaf(a2,b3,acc[11]);
    acc[12] = fmaf(a3,b0,acc[12]); acc[13] = fmaf(a3,b1,acc[13]);
    acc[14] = fmaf(a3,b2,acc[14]); acc[15] = fmaf(a3,b3,acc[15]);
  }
  #pragma unroll
  for (int m = 1; m < 64; m <<= 1)
    #pragma unroll
    for (int u = 0; u < 16; ++u) acc[u] += __shfl_xor(acc[u], m, 64);
  if (lane == 0){
    float sA[4], sB[4];
    #pragma unroll
    for (int i = 0; i < 4; ++i){ sA[i] = invA[offA[i]]; sB[i] = invB[offB[i]]; }
    float4* o = (float4*)(scoresOut + p*16);
    #pragma unroll
    for (int i = 0; i < 4; ++i)
      o[i] = make_float4(acc[i*4+0]*sA[i]*sB[0], acc[i*4+1]*sA[i]*sB[1],
                         acc[i*4+2]*sA[i]*sB[2], acc[i*4+3]*sA[i]*sB[3]);
  }
}

// ---------------- 7. final matching logic + outputs ----------------
__global__ void final_k(const float* __restrict__ scores, const int4* __restrict__ pts,
                        const int* __restrict__ validArr, float* __restrict__ out){
  int p = blockIdx.x * blockDim.x + threadIdx.x;
  float sc[16];
  #pragma unroll
  for (int u = 0; u < 16; ++u) sc[u] = scores[p*16 + u];

  int matchA[4]; float ratioA[4], scoreA[4];
  #pragma unroll
  for (int i = 0; i < 4; ++i){
    int bi = 0; float bv = sc[i*4];
    #pragma unroll
    for (int j = 1; j < 4; ++j) if (sc[i*4+j] > bv){ bv = sc[i*4+j]; bi = j; }
    float sv = -3.402823466e38f;
    #pragma unroll
    for (int j = 0; j < 4; ++j) if (j != bi && sc[i*4+j] > sv){ sv = sc[i*4+j]; }
    matchA[i] = bi;
    float d0 = 2.f - 2.f*bv, d1 = 2.f - 2.f*sv;
    ratioA[i] = d0 / (d1 + EPSF); scoreA[i] = d0;
  }
  int matchB[4]; float ratioB[4];
  #pragma unroll
  for (int j = 0; j < 4; ++j){
    int bi = 0; float bv = sc[j];
    #pragma unroll
    for (int i = 1; i < 4; ++i) if (sc[i*4+j] > bv){ bv = sc[i*4+j]; bi = i; }
    float sv = -3.402823466e38f;
    #pragma unroll
    for (int i = 0; i < 4; ++i) if (i != bi && sc[i*4+j] > sv){ sv = sc[i*4+j]; }
    matchB[j] = bi;
    float d0 = 2.f - 2.f*bv, d1 = 2.f - 2.f*sv;
    ratioB[j] = d0 / (d1 + EPSF);
  }
  bool m[4];
  #pragma unroll
  for (int i = 0; i < 4; ++i)
    m[i] = (fminf(ratioA[i], ratioB[i]) < RREFINE) && (matchB[matchA[i]] == i);
  float smk[4];
  #pragma unroll
  for (int i = 0; i < 4; ++i) smk[i] = m[i] ? scoreA[i] : 5.0f;
  int d0i = 0; float d0v = smk[0];
  #pragma unroll
  for (int i = 1; i < 4; ++i) if (smk[i] > d0v){ d0v = smk[i]; d0i = i; }
  int d1i = -1; float d1v = -3.402823466e38f;
  #pragma unroll
  for (int i = 0; i < 4; ++i) if (i != d0i && smk[i] > d1v){ d1v = smk[i]; d1i = i; }
  m[d0i] = false; m[d1i] = false;
  bool v = validArr[p] != 0;
  int4 q = pts[p];
  const int nbx[4] = {0,0,1,1}, nby[4] = {0,1,0,1};
  #pragma unroll
  for (int i = 0; i < 4; ++i){
    out[           p*4 + i] = (float)(2*q.x + nbx[i]);
    out[  P1*4   + p*4 + i] = (float)(2*q.y + nby[i]);
    out[2*P1*4   + p*4 + i] = (float)(2*q.z + nbx[matchA[i]]);
    out[3*P1*4   + p*4 + i] = (float)(2*q.w + nby[matchA[i]]);
    out[4*P1*4   + p*4 + i] = (m[i] && v) ? 1.0f : 0.0f;
  }
}

// ---------------- launch ----------------
extern "C" void kernel_launch(void* const* d_in, const int* in_sizes, int n_in,
                              void* d_out, int out_size, void* d_ws, size_t ws_size,
                              hipStream_t stream) {
  const float* mapA = (const float*)d_in[0];
  const float* mapB = (const float*)d_in[1];
  const float* actA = (const float*)d_in[2];
  const float* actB = (const float*)d_in[3];
  float* out = (float*)d_out;

  // workspace partition
  unsigned short* Ah = (unsigned short*)d_ws;                 // K-major [16][P1][32] bf16
  unsigned short* Al = Ah + (size_t)P1*CH;
  unsigned short* Bh = Al + (size_t)P1*CH;
  unsigned short* Bl = Bh + (size_t)P1*CH;
  unsigned long long* rowCand = (unsigned long long*)(Bl + (size_t)P1*CH);  // NTT*P1*2
  unsigned long long* colCand = rowCand + (size_t)NTT*P1*2;
  unsigned long long* rowTop  = colCand + (size_t)NTT*P1*2;
  unsigned long long* rowSec  = rowTop + P1;
  unsigned long long* colTop  = rowSec + P1;
  unsigned long long* colSec  = colTop + P1;
  float* inv1 = (float*)(colSec + P1);
  float* inv2 = inv1 + P1;
  float* invA = inv2 + P1;
  float* invB = invA + P2;
  int4*  pts  = (int4*)(invB + P2);
  int*   validArr = (int*)(pts + P1);
  float* tA = (float*)(validArr + P1);                        // [P2][512] fp32
  float* tB = tA + (size_t)P2*CH;
  size_t needBytes = (size_t)((char*)(tB + (size_t)P2*CH) - (char*)d_ws);
  const bool useT = ws_size >= needBytes;

  float* scoresOut = out + 4*P1*4 + P1*4;   // after refined_A/B + mask

  desc_norm <<<2*P1/256, 256, 0, stream>>>(mapA, mapB, inv1, inv2);
  act_norm  <<<2*P2/256, 256, 0, stream>>>(actA, actB, invA, invB);
  prep_split<<<dim3(P1/64, CH/64), 256, 0, stream>>>(mapA, inv1, Ah, Al);
  prep_split<<<dim3(P1/64, CH/64), 256, 0, stream>>>(mapB, inv2, Bh, Bl);
  sim_mfma  <<<NTT*NTT, 512, 0, stream>>>(Ah, Al, Bh, Bl, rowCand, colCand);
  merge_cand<<<P1/256, 256, 0, stream>>>(rowCand, rowTop, rowSec);
  merge_cand<<<P1/256, 256, 0, stream>>>(colCand, colTop, colSec);
  match_k   <<<P1/256, 256, 0, stream>>>(rowTop, rowSec, colTop, colSec, pts, validArr);
  if (useT){
    act_transpose<<<dim3(P2/64, CH/64, 2), 256, 0, stream>>>(actA, actB, tA, tB);
    refine_t <<<P1*64/256, 256, 0, stream>>>(tA, tB, invA, invB, pts, scoresOut);
  } else {
    refine   <<<P1*64/256, 256, 0, stream>>>(actA, actB, invA, invB, pts, scoresOut);
  }
  final_k   <<<P1/256, 256, 0, stream>>>(scoresOut, pts, validArr, out);
}

// Round 5
// 1669.411 us; speedup vs baseline: 1.0565x; 1.0565x over previous
//
#include <hip/hip_runtime.h>
#include <stdint.h>

// ---------------- problem constants ----------------
#define CH 512
#define W1 96
#define P1 (W1*W1)        // 9216 descriptor pixels per map
#define W2 192
#define P2 (W2*W2)        // 36864 activation pixels per map
#define TILE 128
#define NT 72             // 9216/128 tiles per dimension
#define BK 32             // K-chunk
#define NKS (CH/BK)       // 16 K-steps
#define EPSF 1e-8f
#define RDENSE 0.95f
#define RREFINE 0.9f

typedef __attribute__((ext_vector_type(8))) short bf16x8_t;
typedef __attribute__((ext_vector_type(4))) float f32x4_t;

// ---- packed (value,index): total order, ties -> lower index wins ----
__device__ __forceinline__ unsigned enc_f32(float f){
  unsigned u = __float_as_uint(f);
  return (u & 0x80000000u) ? ~u : (u | 0x80000000u);
}
__device__ __forceinline__ float dec_f32(unsigned e){
  unsigned u = (e & 0x80000000u) ? (e & 0x7FFFFFFFu) : ~e;
  return __uint_as_float(u);
}
__device__ __forceinline__ unsigned long long packVI(float v, int idx){
  return (((unsigned long long)enc_f32(v)) << 32) | (unsigned)(~(unsigned)idx);
}
__device__ __forceinline__ float packedVal(unsigned long long p){ return dec_f32((unsigned)(p >> 32)); }
__device__ __forceinline__ int packedIdx(unsigned long long p){ return (int)(~(unsigned)(p & 0xFFFFFFFFull)); }
__device__ __forceinline__ void merge2(unsigned long long &b, unsigned long long &s, unsigned long long c){
  if (c > b){ s = b; b = c; } else if (c > s){ s = c; }
}

// bf16 round-to-nearest-even
__device__ __forceinline__ unsigned short f2bf(float f){
  unsigned u = __float_as_uint(f);
  unsigned r = (u + 0x7FFFu + ((u >> 16) & 1u)) >> 16;
  return (unsigned short)r;
}

__device__ __forceinline__ void gload16(const void* g, void* l){
  __builtin_amdgcn_global_load_lds(
      (const __attribute__((address_space(1))) unsigned int*)g,
      (__attribute__((address_space(3))) unsigned int*)l, 16, 0, 0);
}

// ---------------- 1. descriptor inverse norms ----------------
__global__ void desc_norm(const float* __restrict__ mA, const float* __restrict__ mB,
                          float* __restrict__ inv1, float* __restrict__ inv2){
  int p = blockIdx.x * blockDim.x + threadIdx.x;
  const float* m = (p < P1) ? mA : mB;
  float* o = (p < P1) ? inv1 : inv2;
  int pix = (p < P1) ? p : p - P1;
  float s = 0.f;
  for (int c = 0; c < CH; ++c){ float v = m[c*P1 + pix]; s += v*v; }
  o[pix] = 1.0f / sqrtf(s);
}

// ---------------- 2. activation inverse norms ----------------
__global__ void act_norm(const float* __restrict__ aA, const float* __restrict__ aB,
                         float* __restrict__ invA, float* __restrict__ invB){
  int p = blockIdx.x * blockDim.x + threadIdx.x;
  const float* m = (p < P2) ? aA : aB;
  float* o = (p < P2) ? invA : invB;
  int pix = (p < P2) ? p : p - P2;
  float s = 0.f;
  for (int c = 0; c < CH; ++c){ float v = m[(size_t)c*P2 + pix]; s += v*v; }
  o[pix] = 1.0f / sqrtf(s);
}

// ---------------- 2b. normalize + split fp32 -> bf16 hi/lo, K-MAJOR layout ----------------
// out layout: panel[kb][pix][32] bf16, kb = c/32. Within each row (32 ch = 4 chunks of
// 16 B), chunks stored permuted: stored_chunk = logical_chunk ^ ((pix>>1)&3), so that
// LINEAR global_load_lds staging lands the XOR-swizzle in LDS (rule #21); ds_read
// applies the same XOR.
__global__ __launch_bounds__(256)
void prep_split(const float* __restrict__ src, const float* __restrict__ inv,
                unsigned short* __restrict__ hi, unsigned short* __restrict__ lo){
  __shared__ float tile[64][65];
  const int pixBase = blockIdx.x * 64;
  const int chBase  = blockIdx.y * 64;
  const int t = threadIdx.x;
  #pragma unroll
  for (int rep = 0; rep < 16; ++rep){
    int idx = rep*256 + t;
    int c = idx >> 6, p = idx & 63;
    tile[c][p] = src[(chBase + c)*P1 + pixBase + p];
  }
  __syncthreads();
  const int p = t >> 2, cg = (t & 3) * 16;
  const int pix = pixBase + p;
  const float iv = inv[pix];
  unsigned short hbuf[16], lbuf[16];
  #pragma unroll
  for (int j = 0; j < 16; ++j){
    float v = tile[cg + j][p] * iv;
    unsigned short h = f2bf(v);
    float hv = __uint_as_float((unsigned)h << 16);
    lbuf[j] = f2bf(v - hv);
    hbuf[j] = h;
  }
  const int c0 = chBase + cg;
  const int kb = c0 >> 5;             // K-block index
  const int ck0 = (c0 & 31) >> 3;     // logical chunk 0 or 2
  const int sz = (pix >> 1) & 3;
  size_t base = (size_t)kb*(P1*32) + (size_t)pix*32;
  *(uint4*)(hi + base + ((ck0    ^sz)<<3)) = ((const uint4*)hbuf)[0];
  *(uint4*)(hi + base + (((ck0+1)^sz)<<3)) = ((const uint4*)hbuf)[1];
  *(uint4*)(lo + base + ((ck0    ^sz)<<3)) = ((const uint4*)lbuf)[0];
  *(uint4*)(lo + base + (((ck0+1)^sz)<<3)) = ((const uint4*)lbuf)[1];
}

// ---------------- 3. MFMA sim-GEMM, 128x128 tile, dbuf, trickled staging ----------------
// 4 waves (2x2), wave tile 64x64 (4x4 frags of 16x16x32), 3-pass split bf16.
// LDS: 2 x 32KB dbuf {Ah,Al,Bh,Bl}[128 rows][32k] -> 2 blocks/CU (independent barriers).
// Staging loads issued in 4 clusters of 2 per wave, pinned between MFMA clusters by
// sched_barrier(0) -> steady trickle instead of a 64-load burst.
// XCD 2-D regions: each XCD owns a 72rt x 9ct column band (B slices L2-resident).
__global__ __launch_bounds__(256, 2)
void sim_mfma(const unsigned short* __restrict__ Ah, const unsigned short* __restrict__ Al,
              const unsigned short* __restrict__ Bh, const unsigned short* __restrict__ Bl,
              unsigned long long* __restrict__ rowCand,
              unsigned long long* __restrict__ colCand){
  __shared__ __align__(16) char lds[65536];     // 2 x 32KB

  const int bid = blockIdx.x;                   // 5184 = 72*72
  const int xcd = bid & 7, local = bid >> 3;    // local in [0,648)
  const int rt = local / 9;                     // 0..71 (streams)
  const int ct = xcd * 9 + (local % 9);         // 9-col band per XCD (L2-resident B)
  const int rBase = rt * TILE, cBase = ct * TILE;

  const int t = threadIdx.x;
  const int w = t >> 6, lane = t & 63;
  const int wr = w >> 1, wc = w & 1;            // wave grid 2x2
  const int l15 = lane & 15, lj = lane >> 4;

  // staging: wave w stages panel w's slice (8KB = 8 x 1KB linear loads)
  const unsigned short* pptr = (w==0)?Ah:(w==1)?Al:(w==2)?Bh:Bl;
  const int Base = (w < 2) ? rBase : cBase;
  const char* gpan = (const char*)pptr + (size_t)Base*64;
  char* const myLds0 = lds + w*8192;            // panel w region in buffer 0

  // fragment LDS byte-offsets (row*64 + swizzled_chunk*16)
  int aOff[4], bOff[4];
  #pragma unroll
  for (int mi = 0; mi < 4; ++mi){
    int rA = wr*64 + mi*16 + l15;
    aOff[mi] = rA*64 + ((lj ^ ((rA >> 1) & 3)) << 4);
  }
  #pragma unroll
  for (int ni = 0; ni < 4; ++ni){
    int rB = wc*64 + ni*16 + l15;
    bOff[ni] = rB*64 + ((lj ^ ((rB >> 1) & 3)) << 4);
  }

  f32x4_t acc[4][4];
  #pragma unroll
  for (int i = 0; i < 4; ++i)
    #pragma unroll
    for (int j = 0; j < 4; ++j)
      #pragma unroll
      for (int r = 0; r < 4; ++r) acc[i][j][r] = 0.f;

  // ---- prologue: stage K-step 0 into buf0 ----
  #pragma unroll
  for (int i = 0; i < 8; ++i)
    gload16(gpan + i*1024 + lane*16, myLds0 + i*1024);
  __syncthreads();

  // ---- main loop ----
  for (int ks = 0; ks < NKS; ++ks){
    const int cur = ks & 1;
    const char* bp = lds + cur*32768;
    char* nb = myLds0 + (cur^1)*32768;
    const char* gb = gpan + (size_t)(ks+1)*(P1*64);
    const bool pf = (ks + 1 < NKS);

    bf16x8_t ahf[4], alf[4], bhf[4], blf[4];
    #pragma unroll
    for (int mi = 0; mi < 4; ++mi){
      ahf[mi] = *(const bf16x8_t*)(bp + aOff[mi]);
      alf[mi] = *(const bf16x8_t*)(bp + 8192 + aOff[mi]);
    }
    #pragma unroll
    for (int ni = 0; ni < 4; ++ni){
      bhf[ni] = *(const bf16x8_t*)(bp + 16384 + bOff[ni]);
      blf[ni] = *(const bf16x8_t*)(bp + 24576 + bOff[ni]);
    }
    #pragma unroll
    for (int ni = 0; ni < 4; ++ni){
      if (pf){
        gload16(gb + (ni*2+0)*1024 + lane*16, nb + (ni*2+0)*1024);
        gload16(gb + (ni*2+1)*1024 + lane*16, nb + (ni*2+1)*1024);
      }
      __builtin_amdgcn_sched_barrier(0);        // pin issue position of the trickle
      #pragma unroll
      for (int mi = 0; mi < 4; ++mi){
        acc[mi][ni] = __builtin_amdgcn_mfma_f32_16x16x32_bf16(ahf[mi], bhf[ni], acc[mi][ni], 0, 0, 0);
        acc[mi][ni] = __builtin_amdgcn_mfma_f32_16x16x32_bf16(ahf[mi], blf[ni], acc[mi][ni], 0, 0, 0);
        acc[mi][ni] = __builtin_amdgcn_mfma_f32_16x16x32_bf16(alf[mi], bhf[ni], acc[mi][ni], 0, 0, 0);
      }
    }
    __syncthreads();   // drains this step's trickled loads after the compute window
  }

  // ---- fused top-2 epilogue. C/D layout: col=lane&15, row=(lane>>4)*4+reg ----
  // scratch overlays buf0 (free after final barrier)
  unsigned long long (*rowScr)[2][2] = (unsigned long long (*)[2][2])(lds);          // 4KB
  unsigned long long (*colScr)[2][2] = (unsigned long long (*)[2][2])(lds + 8192);   // 4KB

  #pragma unroll
  for (int mi = 0; mi < 4; ++mi){
    #pragma unroll
    for (int reg = 0; reg < 4; ++reg){
      unsigned long long b = 0ull, s = 0ull;
      #pragma unroll
      for (int ni = 0; ni < 4; ++ni){
        int col = cBase + wc*64 + ni*16 + l15;
        merge2(b, s, packVI(acc[mi][ni][reg], col));
      }
      #pragma unroll
      for (int m = 1; m < 16; m <<= 1){
        unsigned long long ob = __shfl_xor(b, m, 64);
        unsigned long long os = __shfl_xor(s, m, 64);
        merge2(b, s, ob); merge2(b, s, os);
      }
      if (l15 == 0){
        int rowLoc = wr*64 + mi*16 + lj*4 + reg;
        rowScr[rowLoc][wc][0] = b; rowScr[rowLoc][wc][1] = s;
      }
    }
  }
  #pragma unroll
  for (int ni = 0; ni < 4; ++ni){
    unsigned long long b = 0ull, s = 0ull;
    #pragma unroll
    for (int mi = 0; mi < 4; ++mi)
      #pragma unroll
      for (int reg = 0; reg < 4; ++reg){
        int row = rBase + wr*64 + mi*16 + lj*4 + reg;
        merge2(b, s, packVI(acc[mi][ni][reg], row));
      }
    #pragma unroll
    for (int m = 16; m < 64; m <<= 1){
      unsigned long long ob = __shfl_xor(b, m, 64);
      unsigned long long os = __shfl_xor(s, m, 64);
      merge2(b, s, ob); merge2(b, s, os);
    }
    if (lj == 0){
      int colLoc = wc*64 + ni*16 + l15;
      colScr[colLoc][wr][0] = b; colScr[colLoc][wr][1] = s;
    }
  }
  __syncthreads();
  if (t < TILE){
    unsigned long long b = 0ull, s = 0ull;
    #pragma unroll
    for (int j = 0; j < 2; ++j){ merge2(b, s, rowScr[t][j][0]); merge2(b, s, rowScr[t][j][1]); }
    rowCand[((long long)ct*P1 + rBase + t)*2 + 0] = b;
    rowCand[((long long)ct*P1 + rBase + t)*2 + 1] = s;
  } else {
    int c = t - TILE;
    unsigned long long b = 0ull, s = 0ull;
    #pragma unroll
    for (int j = 0; j < 2; ++j){ merge2(b, s, colScr[c][j][0]); merge2(b, s, colScr[c][j][1]); }
    colCand[((long long)rt*P1 + cBase + c)*2 + 0] = b;
    colCand[((long long)rt*P1 + cBase + c)*2 + 1] = s;
  }
}

// ---------------- 4. merge per-tile candidates -> global top-2 ----------------
__global__ void merge_cand(const unsigned long long* __restrict__ cand,
                           unsigned long long* __restrict__ top,
                           unsigned long long* __restrict__ sec){
  int p = blockIdx.x * blockDim.x + threadIdx.x;
  unsigned long long b = 0ull, s = 0ull;
  for (int tile = 0; tile < NT; ++tile){
    merge2(b, s, cand[((long long)tile*P1 + p)*2 + 0]);
    merge2(b, s, cand[((long long)tile*P1 + p)*2 + 1]);
  }
  top[p] = b; sec[p] = s;
}

// ---------------- 5. mutual-NN + ratio + border mask ----------------
__global__ void match_k(const unsigned long long* __restrict__ rowTop,
                        const unsigned long long* __restrict__ rowSec,
                        const unsigned long long* __restrict__ colTop,
                        const unsigned long long* __restrict__ colSec,
                        int4* __restrict__ pts, int* __restrict__ validArr){
  int p = blockIdx.x * blockDim.x + threadIdx.x;
  unsigned long long rT = rowTop[p], rS = rowSec[p];
  float s0 = packedVal(rT), s1 = packedVal(rS);
  int nn12 = packedIdx(rT);
  float r12 = (2.f - 2.f*s0) / (2.f - 2.f*s1 + EPSF);
  unsigned long long cT = colTop[nn12], cS = colSec[nn12];
  int nn21 = packedIdx(cT);
  float r21 = (2.f - 2.f*packedVal(cT)) / (2.f - 2.f*packedVal(cS) + EPSF);
  int xA = p % W1, yA = p / W1, xB = nn12 % W1, yB = nn12 / W1;
  bool border = (xA==0)||(xA==W1-1)||(yA==0)||(yA==W1-1)||
                (xB==0)||(xB==W1-1)||(yB==0)||(yB==W1-1);
  bool valid = (nn21 == p) && (r12 <= RDENSE) && (r21 <= RDENSE) && !border;
  pts[p] = valid ? make_int4(xA,yA,xB,yB) : make_int4(0,0,0,0);
  validArr[p] = valid ? 1 : 0;
}

// ---------------- 6a. activation transpose: [512][P2] -> [P2][512] fp32 ----------------
__global__ __launch_bounds__(256)
void act_transpose(const float* __restrict__ aA, const float* __restrict__ aB,
                   float* __restrict__ tA, float* __restrict__ tB){
  __shared__ float tile[64][65];
  const int pixBase = blockIdx.x * 64;
  const int chBase  = blockIdx.y * 64;
  const float* src = blockIdx.z ? aB : aA;
  float*       dst = blockIdx.z ? tB : tA;
  const int t = threadIdx.x;
  #pragma unroll
  for (int rep = 0; rep < 16; ++rep){
    int idx = rep*256 + t;
    int c = idx >> 6, p = idx & 63;
    tile[c][p] = src[(size_t)(chBase + c)*P2 + pixBase + p];
  }
  __syncthreads();
  const int p = t >> 2, cg = (t & 3) * 16;
  size_t base = (size_t)(pixBase + p)*CH + chBase + cg;
  #pragma unroll
  for (int q = 0; q < 4; ++q){
    float4 v = make_float4(tile[cg+q*4+0][p], tile[cg+q*4+1][p],
                           tile[cg+q*4+2][p], tile[cg+q*4+3][p]);
    *(float4*)(dst + base + q*4) = v;
  }
}

// ---------------- 6b. refine with transposed activations (coalesced) ----------------
__global__ __launch_bounds__(256)
void refine_t(const float* __restrict__ tA, const float* __restrict__ tB,
              const float* __restrict__ invA, const float* __restrict__ invB,
              const int4* __restrict__ pts, float* __restrict__ scoresOut){
  int p = (blockIdx.x * blockDim.x + threadIdx.x) >> 6;
  int lane = threadIdx.x & 63;
  int4 q = pts[p];
  const int nbx[4] = {0,0,1,1}, nby[4] = {0,1,0,1};
  int offA[4], offB[4];
  #pragma unroll
  for (int i = 0; i < 4; ++i){
    offA[i] = (2*q.y + nby[i])*W2 + 2*q.x + nbx[i];
    offB[i] = (2*q.w + nby[i])*W2 + 2*q.z + nbx[i];
  }
  float a[4][8], b[4][8];
  #pragma unroll
  for (int i = 0; i < 4; ++i){
    const float* pa = tA + (size_t)offA[i]*CH + lane*8;
    *(float4*)&a[i][0] = *(const float4*)pa;
    *(float4*)&a[i][4] = *(const float4*)(pa + 4);
    const float* pb = tB + (size_t)offB[i]*CH + lane*8;
    *(float4*)&b[i][0] = *(const float4*)pb;
    *(float4*)&b[i][4] = *(const float4*)(pb + 4);
  }
  float acc[16] = {};
  #pragma unroll
  for (int ch = 0; ch < 8; ++ch)
    #pragma unroll
    for (int i = 0; i < 4; ++i)
      #pragma unroll
      for (int j = 0; j < 4; ++j)
        acc[i*4+j] = fmaf(a[i][ch], b[j][ch], acc[i*4+j]);
  #pragma unroll
  for (int m = 1; m < 64; m <<= 1)
    #pragma unroll
    for (int u = 0; u < 16; ++u) acc[u] += __shfl_xor(acc[u], m, 64);
  if (lane == 0){
    float sA[4], sB[4];
    #pragma unroll
    for (int i = 0; i < 4; ++i){ sA[i] = invA[offA[i]]; sB[i] = invB[offB[i]]; }
    float4* o = (float4*)(scoresOut + p*16);
    #pragma unroll
    for (int i = 0; i < 4; ++i)
      o[i] = make_float4(acc[i*4+0]*sA[i]*sB[0], acc[i*4+1]*sA[i]*sB[1],
                         acc[i*4+2]*sA[i]*sB[2], acc[i*4+3]*sA[i]*sB[3]);
  }
}

// ---------------- 6c. fallback refine (original layout, gathered) ----------------
__global__ __launch_bounds__(256)
void refine(const float* __restrict__ actA, const float* __restrict__ actB,
            const float* __restrict__ invA, const float* __restrict__ invB,
            const int4* __restrict__ pts, float* __restrict__ scoresOut){
  int p = (blockIdx.x * blockDim.x + threadIdx.x) >> 6;
  int lane = threadIdx.x & 63;
  int4 q = pts[p];
  const int nbx[4] = {0,0,1,1}, nby[4] = {0,1,0,1};
  int offA[4], offB[4];
  #pragma unroll
  for (int i = 0; i < 4; ++i){
    offA[i] = (2*q.y + nby[i])*W2 + 2*q.x + nbx[i];
    offB[i] = (2*q.w + nby[i])*W2 + 2*q.z + nbx[i];
  }
  float acc[16] = {};
  #pragma unroll
  for (int k = 0; k < 8; ++k){
    int c = lane + 64*k;
    size_t base = (size_t)c * P2;
    float a0 = actA[base+offA[0]], a1 = actA[base+offA[1]],
          a2 = actA[base+offA[2]], a3 = actA[base+offA[3]];
    float b0 = actB[base+offB[0]], b1 = actB[base+offB[1]],
          b2 = actB[base+offB[2]], b3 = actB[base+offB[3]];
    acc[ 0] = fmaf(a0,b0,acc[ 0]); acc[ 1] = fmaf(a0,b1,acc[ 1]);
    acc[ 2] = fmaf(a0,b2,acc[ 2]); acc[ 3] = fmaf(a0,b3,acc[ 3]);
    acc[ 4] = fmaf(a1,b0,acc[ 4]); acc[ 5] = fmaf(a1,b1,acc[ 5]);
    acc[ 6] = fmaf(a1,b2,acc[ 6]); acc[ 7] = fmaf(a1,b3,acc[ 7]);
    acc[ 8] = fmaf(a2,b0,acc[ 8]); acc[ 9] = fmaf(a2,b1,acc[ 9]);
    acc[10] = fmaf(a2,b2,acc[10]); acc[11] = fmaf(a2,b3,acc[11]);
    acc[12] = fmaf(a3,b0,acc[12]); acc[13] = fmaf(a3,b1,acc[13]);
    acc[14] = fmaf(a3,b2,acc[14]); acc[15] = fmaf(a3,b3,acc[15]);
  }
  #pragma unroll
  for (int m = 1; m < 64; m <<= 1)
    #pragma unroll
    for (int u = 0; u < 16; ++u) acc[u] += __shfl_xor(acc[u], m, 64);
  if (lane == 0){
    float sA[4], sB[4];
    #pragma unroll
    for (int i = 0; i < 4; ++i){ sA[i] = invA[offA[i]]; sB[i] = invB[offB[i]]; }
    float4* o = (float4*)(scoresOut + p*16);
    #pragma unroll
    for (int i = 0; i < 4; ++i)
      o[i] = make_float4(acc[i*4+0]*sA[i]*sB[0], acc[i*4+1]*sA[i]*sB[1],
                         acc[i*4+2]*sA[i]*sB[2], acc[i*4+3]*sA[i]*sB[3]);
  }
}

// ---------------- 7. final matching logic + outputs ----------------
__global__ void final_k(const float* __restrict__ scores, const int4* __restrict__ pts,
                        const int* __restrict__ validArr, float* __restrict__ out){
  int p = blockIdx.x * blockDim.x + threadIdx.x;
  float sc[16];
  #pragma unroll
  for (int u = 0; u < 16; ++u) sc[u] = scores[p*16 + u];

  int matchA[4]; float ratioA[4], scoreA[4];
  #pragma unroll
  for (int i = 0; i < 4; ++i){
    int bi = 0; float bv = sc[i*4];
    #pragma unroll
    for (int j = 1; j < 4; ++j) if (sc[i*4+j] > bv){ bv = sc[i*4+j]; bi = j; }
    float sv = -3.402823466e38f;
    #pragma unroll
    for (int j = 0; j < 4; ++j) if (j != bi && sc[i*4+j] > sv){ sv = sc[i*4+j]; }
    matchA[i] = bi;
    float d0 = 2.f - 2.f*bv, d1 = 2.f - 2.f*sv;
    ratioA[i] = d0 / (d1 + EPSF); scoreA[i] = d0;
  }
  int matchB[4]; float ratioB[4];
  #pragma unroll
  for (int j = 0; j < 4; ++j){
    int bi = 0; float bv = sc[j];
    #pragma unroll
    for (int i = 1; i < 4; ++i) if (sc[i*4+j] > bv){ bv = sc[i*4+j]; bi = i; }
    float sv = -3.402823466e38f;
    #pragma unroll
    for (int i = 0; i < 4; ++i) if (i != bi && sc[i*4+j] > sv){ sv = sc[i*4+j]; }
    matchB[j] = bi;
    float d0 = 2.f - 2.f*bv, d1 = 2.f - 2.f*sv;
    ratioB[j] = d0 / (d1 + EPSF);
  }
  bool m[4];
  #pragma unroll
  for (int i = 0; i < 4; ++i)
    m[i] = (fminf(ratioA[i], ratioB[i]) < RREFINE) && (matchB[matchA[i]] == i);
  float smk[4];
  #pragma unroll
  for (int i = 0; i < 4; ++i) smk[i] = m[i] ? scoreA[i] : 5.0f;
  int d0i = 0; float d0v = smk[0];
  #pragma unroll
  for (int i = 1; i < 4; ++i) if (smk[i] > d0v){ d0v = smk[i]; d0i = i; }
  int d1i = -1; float d1v = -3.402823466e38f;
  #pragma unroll
  for (int i = 0; i < 4; ++i) if (i != d0i && smk[i] > d1v){ d1v = smk[i]; d1i = i; }
  m[d0i] = false; m[d1i] = false;
  bool v = validArr[p] != 0;
  int4 q = pts[p];
  const int nbx[4] = {0,0,1,1}, nby[4] = {0,1,0,1};
  #pragma unroll
  for (int i = 0; i < 4; ++i){
    out[           p*4 + i] = (float)(2*q.x + nbx[i]);
    out[  P1*4   + p*4 + i] = (float)(2*q.y + nby[i]);
    out[2*P1*4   + p*4 + i] = (float)(2*q.z + nbx[matchA[i]]);
    out[3*P1*4   + p*4 + i] = (float)(2*q.w + nby[matchA[i]]);
    out[4*P1*4   + p*4 + i] = (m[i] && v) ? 1.0f : 0.0f;
  }
}

// ---------------- launch ----------------
extern "C" void kernel_launch(void* const* d_in, const int* in_sizes, int n_in,
                              void* d_out, int out_size, void* d_ws, size_t ws_size,
                              hipStream_t stream) {
  const float* mapA = (const float*)d_in[0];
  const float* mapB = (const float*)d_in[1];
  const float* actA = (const float*)d_in[2];
  const float* actB = (const float*)d_in[3];
  float* out = (float*)d_out;

  // workspace partition
  unsigned short* Ah = (unsigned short*)d_ws;                 // K-major [16][P1][32] bf16
  unsigned short* Al = Ah + (size_t)P1*CH;
  unsigned short* Bh = Al + (size_t)P1*CH;
  unsigned short* Bl = Bh + (size_t)P1*CH;
  unsigned long long* rowCand = (unsigned long long*)(Bl + (size_t)P1*CH);  // NT*P1*2
  unsigned long long* colCand = rowCand + (size_t)NT*P1*2;
  unsigned long long* rowTop  = colCand + (size_t)NT*P1*2;
  unsigned long long* rowSec  = rowTop + P1;
  unsigned long long* colTop  = rowSec + P1;
  unsigned long long* colSec  = colTop + P1;
  float* inv1 = (float*)(colSec + P1);
  float* inv2 = inv1 + P1;
  float* invA = inv2 + P1;
  float* invB = invA + P2;
  int4*  pts  = (int4*)(invB + P2);
  int*   validArr = (int*)(pts + P1);
  float* tA = (float*)(validArr + P1);                        // [P2][512] fp32
  float* tB = tA + (size_t)P2*CH;
  size_t needBytes = (size_t)((char*)(tB + (size_t)P2*CH) - (char*)d_ws);
  const bool useT = ws_size >= needBytes;

  float* scoresOut = out + 4*P1*4 + P1*4;   // after refined_A/B + mask

  desc_norm <<<2*P1/256, 256, 0, stream>>>(mapA, mapB, inv1, inv2);
  act_norm  <<<2*P2/256, 256, 0, stream>>>(actA, actB, invA, invB);
  prep_split<<<dim3(P1/64, CH/64), 256, 0, stream>>>(mapA, inv1, Ah, Al);
  prep_split<<<dim3(P1/64, CH/64), 256, 0, stream>>>(mapB, inv2, Bh, Bl);
  sim_mfma  <<<NT*NT, 256, 0, stream>>>(Ah, Al, Bh, Bl, rowCand, colCand);
  merge_cand<<<P1/256, 256, 0, stream>>>(rowCand, rowTop, rowSec);
  merge_cand<<<P1/256, 256, 0, stream>>>(colCand, colTop, colSec);
  match_k   <<<P1/256, 256, 0, stream>>>(rowTop, rowSec, colTop, colSec, pts, validArr);
  if (useT){
    act_transpose<<<dim3(P2/64, CH/64, 2), 256, 0, stream>>>(actA, actB, tA, tB);
    refine_t <<<P1*64/256, 256, 0, stream>>>(tA, tB, invA, invB, pts, scoresOut);
  } else {
    refine   <<<P1*64/256, 256, 0, stream>>>(actA, actB, invA, invB, pts, scoresOut);
  }
  final_k   <<<P1/256, 256, 0, stream>>>(scoresOut, pts, validArr, out);
}